// Round 1
// baseline (549.347 us; speedup 1.0000x reference)
//
#include <hip/hip_runtime.h>

#define BATCH 32
#define CDIM 512
#define NCL 27
#define HWDIM 3136            // 56*56
#define NPIX (BATCH * HWDIM)  // 100352
#define TILES_PER_B 49        // 3136 / 64
#define NBLK (BATCH * TILES_PER_B)  // 1568
#define CPG 128               // channels per y-group (512/4)

// ---------------------------------------------------------------------------
// Kernel 1: L2-normalize the 27 codebook rows into workspace.
// One 64-thread block per cluster row; each lane handles 8 channels.
// ---------------------------------------------------------------------------
__global__ void norm_clusters_k(const float* __restrict__ cl,
                                float* __restrict__ cn) {
    const int n = blockIdx.x;
    const int lane = threadIdx.x;  // 0..63
    float v[8];
    float ss = 0.f;
#pragma unroll
    for (int k = 0; k < 8; ++k) {
        v[k] = cl[n * CDIM + k * 64 + lane];
        ss += v[k] * v[k];
    }
#pragma unroll
    for (int off = 32; off > 0; off >>= 1) ss += __shfl_down(ss, off, 64);
    ss = __shfl(ss, 0, 64);
    const float rn = 1.0f / fmaxf(sqrtf(ss), 1e-12f);
#pragma unroll
    for (int k = 0; k < 8; ++k) cn[n * CDIM + k * 64 + lane] = v[k] * rn;
}

// ---------------------------------------------------------------------------
// Kernel 2: main. Block = (64 pixels, 4 channel-groups). Each thread
// accumulates 27 partial dots + |x|^2 over 128 channels; LDS reduction
// across the 4 groups; wave 0 does the per-pixel softmax; all 4 waves
// write the probs coalesced; per-block loss partial to workspace.
// ---------------------------------------------------------------------------
__global__ __launch_bounds__(256) void cluster_main_k(
    const float* __restrict__ x, const float* __restrict__ cn,
    float* __restrict__ out_probs,   // = d_out + 1
    float* __restrict__ partials) {
    __shared__ float red[4][64][29];  // [group][pixel][27 accs + ss], pad 29

    const int lane = threadIdx.x;  // pixel within tile
    const int g = threadIdx.y;     // channel group
    const int b = blockIdx.x / TILES_PER_B;
    const int tile = blockIdx.x % TILES_PER_B;

    const float* xb = x + ((size_t)b * CDIM + (size_t)g * CPG) * HWDIM +
                      (size_t)tile * 64 + lane;

    float acc[NCL];
#pragma unroll
    for (int n = 0; n < NCL; ++n) acc[n] = 0.f;
    float ss = 0.f;

    for (int c = 0; c < CPG; c += 4) {
        const float xv0 = xb[(size_t)(c + 0) * HWDIM];
        const float xv1 = xb[(size_t)(c + 1) * HWDIM];
        const float xv2 = xb[(size_t)(c + 2) * HWDIM];
        const float xv3 = xb[(size_t)(c + 3) * HWDIM];
        ss += xv0 * xv0 + xv1 * xv1 + xv2 * xv2 + xv3 * xv3;
        // wave-uniform index -> scalar (s_load) cluster operands
        const float* cc = cn + g * CPG + c;
#pragma unroll
        for (int n = 0; n < NCL; ++n) {
            acc[n] += xv0 * cc[n * CDIM + 0] + xv1 * cc[n * CDIM + 1] +
                      xv2 * cc[n * CDIM + 2] + xv3 * cc[n * CDIM + 3];
        }
    }

#pragma unroll
    for (int n = 0; n < NCL; ++n) red[g][lane][n] = acc[n];
    red[g][lane][27] = ss;
    __syncthreads();

    // Step 1: reduce across the 4 groups. 64 pix * 28 vals = 1792 / 256 = 7
    const int t = g * 64 + lane;
#pragma unroll
    for (int k = 0; k < 7; ++k) {
        const int v = k * 256 + t;  // 0..1791
        const int pix = v & 63;
        const int j = v >> 6;  // 0..27
        red[0][pix][j] = red[0][pix][j] + red[1][pix][j] + red[2][pix][j] +
                         red[3][pix][j];
    }
    __syncthreads();

    // Step 2: softmax, one thread per pixel (wave 0 only)
    if (g == 0) {
        float s[NCL];
#pragma unroll
        for (int n = 0; n < NCL; ++n) s[n] = red[0][lane][n];
        const float xs = red[0][lane][27];
        const float rn = 1.0f / fmaxf(sqrtf(xs), 1e-12f);
        float m = -1e30f;
#pragma unroll
        for (int n = 0; n < NCL; ++n) {
            s[n] *= rn;  // cosine similarity
            m = fmaxf(m, s[n]);
        }
        float e[NCL];
        float z = 0.f;
#pragma unroll
        for (int n = 0; n < NCL; ++n) {
            e[n] = __expf(2.0f * (s[n] - m));
            z += e[n];
        }
        const float rz = 1.0f / z;
        float dot = 0.f;
#pragma unroll
        for (int n = 0; n < NCL; ++n) {
            const float p = e[n] * rz;
            red[1][lane][n] = p;  // stash probs for coalesced write
            dot += p * s[n];
        }
#pragma unroll
        for (int off = 32; off > 0; off >>= 1)
            dot += __shfl_down(dot, off, 64);
        if (lane == 0) partials[blockIdx.x] = dot;
    }
    __syncthreads();

    // Step 3: coalesced probs writes, all 4 waves. n = g*7+k covers 0..26
    const size_t obase =
        (size_t)b * NCL * HWDIM + (size_t)tile * 64 + lane;
#pragma unroll
    for (int k = 0; k < 7; ++k) {
        const int n = g * 7 + k;
        if (n < NCL) out_probs[obase + (size_t)n * HWDIM] = red[1][lane][n];
    }
}

// ---------------------------------------------------------------------------
// Kernel 3: reduce 1568 per-block partials -> loss scalar
// ---------------------------------------------------------------------------
__global__ void loss_final_k(const float* __restrict__ partials,
                             float* __restrict__ out) {
    __shared__ float sm[4];
    const int t = threadIdx.x;  // 256
    float s = 0.f;
    for (int i = t; i < NBLK; i += 256) s += partials[i];
#pragma unroll
    for (int off = 32; off > 0; off >>= 1) s += __shfl_down(s, off, 64);
    if ((t & 63) == 0) sm[t >> 6] = s;
    __syncthreads();
    if (t == 0) {
        const float tot = sm[0] + sm[1] + sm[2] + sm[3];
        out[0] = -(tot / (float)NPIX);
    }
}

extern "C" void kernel_launch(void* const* d_in, const int* in_sizes, int n_in,
                              void* d_out, int out_size, void* d_ws,
                              size_t ws_size, hipStream_t stream) {
    const float* x = (const float*)d_in[0];        // [32,512,56,56]
    const float* clusters = (const float*)d_in[1]; // [27,512]
    float* out = (float*)d_out;                    // [loss | probs 32*27*56*56]
    float* cn = (float*)d_ws;                      // normalized clusters 27*512
    float* partials = cn + NCL * CDIM;             // 1568 loss partials

    norm_clusters_k<<<NCL, 64, 0, stream>>>(clusters, cn);
    cluster_main_k<<<NBLK, dim3(64, 4), 0, stream>>>(x, cn, out + 1, partials);
    loss_final_k<<<1, 256, 0, stream>>>(partials, out);
}

// Round 2
// 327.849 us; speedup vs baseline: 1.6756x; 1.6756x over previous
//
#include <hip/hip_runtime.h>

#define BATCH 32
#define CDIM 512
#define NCL 27
#define NPAD 28               // padded cluster row (27 + 1) -> 7 float4s
#define HWDIM 3136            // 56*56
#define NPIX (BATCH * HWDIM)  // 100352
#define PXB 128               // pixels per block (P=2 per lane, 64 lanes)
#define NBLK (NPIX / PXB)     // 784
#define CPG 128               // channels per wave (512 / 4 waves)

// ---------------------------------------------------------------------------
// Kernel 1: L2-normalize the 27 codebook rows, store TRANSPOSED + padded:
// cnT[c*28 + n] so the main kernel reads 7 contiguous float4s per channel.
// One wave per cluster row.
// ---------------------------------------------------------------------------
__global__ void norm_clusters_k(const float* __restrict__ cl,
                                float* __restrict__ cnT) {
    const int n = blockIdx.x;
    const int lane = threadIdx.x;  // 0..63
    float v[8];
    float ss = 0.f;
#pragma unroll
    for (int k = 0; k < 8; ++k) {
        v[k] = cl[n * CDIM + k * 64 + lane];
        ss += v[k] * v[k];
    }
#pragma unroll
    for (int off = 32; off > 0; off >>= 1) ss += __shfl_down(ss, off, 64);
    ss = __shfl(ss, 0, 64);
    const float rn = 1.0f / fmaxf(sqrtf(ss), 1e-12f);
#pragma unroll
    for (int k = 0; k < 8; ++k)
        cnT[(size_t)(k * 64 + lane) * NPAD + n] = v[k] * rn;
}

// ---------------------------------------------------------------------------
// Kernel 2: main. Block = 256 threads (4 waves). Each wave: 128 pixels
// (2 per lane, float2) x 128 channels. Per channel: 1 float2 x-load +
// 7 float4 cluster loads (uniform address -> broadcast) + 56 FMAs.
// LDS reduction across the 4 channel-groups, softmax by waves 0/1,
// coalesced scalar prob stores, per-block loss partial.
// ---------------------------------------------------------------------------
__global__ __launch_bounds__(256) void cluster_main_k(
    const float* __restrict__ x, const float* __restrict__ cnT,
    float* __restrict__ out_probs,  // = d_out + 1
    float* __restrict__ partials) {
    __shared__ float red[4][NPAD][PXB];  // 57344 B
    __shared__ float lossred[2];

    const int lane = threadIdx.x;        // 0..63
    const int g = threadIdx.y;           // 0..3 channel group
    const int t = g * 64 + lane;

    // two pixels per lane: p0, p0+1 (never straddle a batch: HWDIM even)
    const int p0 = blockIdx.x * PXB + 2 * lane;
    const int b = p0 / HWDIM;
    const int hw = p0 - b * HWDIM;

    const float* xp = x + (size_t)b * CDIM * HWDIM + hw +
                      (size_t)(g * CPG) * HWDIM;
    const int gbase = __builtin_amdgcn_readfirstlane(g * CPG);
    const float4* cl4 = (const float4*)(cnT + (size_t)gbase * NPAD);

    float2 acc[NCL];
#pragma unroll
    for (int n = 0; n < NCL; ++n) acc[n].x = acc[n].y = 0.f;
    float ssx = 0.f, ssy = 0.f;

#pragma unroll 2
    for (int c = 0; c < CPG; ++c) {
        const float2 xv = *(const float2*)(xp + (size_t)c * HWDIM);
        float4 q[7];
#pragma unroll
        for (int k = 0; k < 7; ++k) q[k] = cl4[c * 7 + k];
        ssx += xv.x * xv.x;
        ssy += xv.y * xv.y;
        const float* cv = (const float*)q;
#pragma unroll
        for (int n = 0; n < NCL; ++n) {
            acc[n].x += xv.x * cv[n];
            acc[n].y += xv.y * cv[n];
        }
    }

    // stage partial sums: red[g][j][px]
#pragma unroll
    for (int n = 0; n < NCL; ++n)
        *(float2*)&red[g][n][2 * lane] = acc[n];
    red[g][27][2 * lane] = ssx;
    red[g][27][2 * lane + 1] = ssy;
    __syncthreads();

    // reduce the 4 groups: 28*128 = 3584 values, 14 per thread
#pragma unroll
    for (int k = 0; k < 14; ++k) {
        const int v = k * 256 + t;
        const int j = v >> 7;
        const int px = v & 127;
        red[0][j][px] = red[0][j][px] + red[1][j][px] + red[2][j][px] +
                        red[3][j][px];
    }
    __syncthreads();

    // softmax: one pixel per thread, waves 0 & 1
    if (t < PXB) {
        const int px = t;
        const float xs = red[0][27][px];
        const float rn = 1.0f / fmaxf(sqrtf(xs), 1e-12f);
        float s[NCL];
        float m = -1e30f;
#pragma unroll
        for (int n = 0; n < NCL; ++n) {
            s[n] = red[0][n][px] * rn;
            m = fmaxf(m, s[n]);
        }
        float e[NCL];
        float z = 0.f;
#pragma unroll
        for (int n = 0; n < NCL; ++n) {
            e[n] = __expf(2.0f * (s[n] - m));
            z += e[n];
        }
        const float rz = 1.0f / z;

        const int p = blockIdx.x * PXB + px;
        const int bb = p / HWDIM;
        const int hh = p - bb * HWDIM;
        float* op = out_probs + (size_t)bb * NCL * HWDIM + hh;
        float dot = 0.f;
#pragma unroll
        for (int n = 0; n < NCL; ++n) {
            const float pr = e[n] * rz;
            op[(size_t)n * HWDIM] = pr;  // lanes -> consecutive hh: coalesced
            dot += pr * s[n];
        }
#pragma unroll
        for (int off = 32; off > 0; off >>= 1)
            dot += __shfl_down(dot, off, 64);
        if (lane == 0) lossred[g] = dot;  // g in {0,1} here
    }
    __syncthreads();
    if (t == 0) partials[blockIdx.x] = lossred[0] + lossred[1];
}

// ---------------------------------------------------------------------------
// Kernel 3: reduce 784 per-block partials -> loss scalar
// ---------------------------------------------------------------------------
__global__ void loss_final_k(const float* __restrict__ partials,
                             float* __restrict__ out) {
    __shared__ float sm[4];
    const int t = threadIdx.x;  // 256
    float s = 0.f;
    for (int i = t; i < NBLK; i += 256) s += partials[i];
#pragma unroll
    for (int off = 32; off > 0; off >>= 1) s += __shfl_down(s, off, 64);
    if ((t & 63) == 0) sm[t >> 6] = s;
    __syncthreads();
    if (t == 0) {
        const float tot = sm[0] + sm[1] + sm[2] + sm[3];
        out[0] = -(tot / (float)NPIX);
    }
}

extern "C" void kernel_launch(void* const* d_in, const int* in_sizes, int n_in,
                              void* d_out, int out_size, void* d_ws,
                              size_t ws_size, hipStream_t stream) {
    const float* x = (const float*)d_in[0];        // [32,512,56,56]
    const float* clusters = (const float*)d_in[1]; // [27,512]
    float* out = (float*)d_out;                    // [loss | probs]
    float* cnT = (float*)d_ws;                     // transposed clusters 512*28
    float* partials = cnT + CDIM * NPAD;           // 784 loss partials

    norm_clusters_k<<<NCL, 64, 0, stream>>>(clusters, cnT);
    cluster_main_k<<<NBLK, dim3(64, 4), 0, stream>>>(x, cnT, out + 1, partials);
    loss_final_k<<<1, 256, 0, stream>>>(partials, out);
}